// Round 12
// baseline (165.850 us; speedup 1.0000x reference)
//
#include <hip/hip_runtime.h>
#include <cstddef>

constexpr int NN  = 40000;   // nodes
constexpr int NE  = 640000;  // edges
constexpr int DIM = 128;     // D_IN == D_OUT
constexpr int CAP = 48;      // per-node neighbor capacity (max deg ~36)
constexpr int PLANE = NN * 64;    // shorts per 64-dim plane (2-plane layout)
constexpr int PL4   = NN * 32;    // shorts per 32-dim plane (4-plane layout)

typedef __attribute__((ext_vector_type(8))) short short8;   // 8 bf16 (4 VGPRs)
typedef __attribute__((ext_vector_type(4))) float floatx4;  // MFMA acc

// fp32 -> bf16 with round-to-nearest-even
__device__ __forceinline__ unsigned short f2bf(float x) {
    union { float f; unsigned int i; } v; v.f = x;
    unsigned int u = v.i;
    return (unsigned short)((u + 0x7fffu + ((u >> 16) & 1u)) >> 16);
}
__device__ __forceinline__ float bflo2f(unsigned int u) {   // low bf16 -> f32
    union { unsigned int i; float f; } v; v.i = u << 16; return v.f;
}
__device__ __forceinline__ float bfhi2f(unsigned int u) {   // high bf16 -> f32
    union { unsigned int i; float f; } v; v.i = u & 0xffff0000u; return v.f;
}

// ---------------------------------------------------------------------------
// Prep: [blocks 0..2499]    cast feat -> BOTH bf16 layouts:
//                           featb2[2][NN][64] (gemm) and featb4[4][NN][32]
//                           (gather; 64B rows = 1 cache line per class)
//       [blocks 2500..2627] transpose+cast W to Wc[4][128][64]
//       [blocks 2628..2784] zero cnt[NN]
// ---------------------------------------------------------------------------
__global__ __launch_bounds__(256) void k_prep(
    const float* __restrict__ feat, const float* __restrict__ Wself,
    const float* __restrict__ Wneigh, unsigned short* __restrict__ featb2,
    unsigned short* __restrict__ featb4, unsigned short* __restrict__ Wc,
    int* __restrict__ cnt)
{
    int b = blockIdx.x, t = threadIdx.x;
    if (b < 2500) {
        int idx8 = b * 256 + t;          // 640000 groups of 8 dims
        int n  = idx8 >> 4;              // 16 groups per row
        int d0 = (idx8 & 15) << 3;       // dim base 0,8,...,120
        const float4* fp =
            reinterpret_cast<const float4*>(feat + (size_t)n * DIM + d0);
        float4 v0 = fp[0], v1 = fp[1];
        unsigned int p0 = (unsigned int)f2bf(v0.x) | ((unsigned int)f2bf(v0.y) << 16);
        unsigned int p1 = (unsigned int)f2bf(v0.z) | ((unsigned int)f2bf(v0.w) << 16);
        unsigned int p2 = (unsigned int)f2bf(v1.x) | ((unsigned int)f2bf(v1.y) << 16);
        unsigned int p3 = (unsigned int)f2bf(v1.z) | ((unsigned int)f2bf(v1.w) << 16);
        uint4 pk = make_uint4(p0, p1, p2, p3);
        // 2-plane layout (gemm staging source)
        *reinterpret_cast<uint4*>(
            featb2 + (size_t)(d0 >> 6) * PLANE + (size_t)n * 64 + (d0 & 63)) = pk;
        // 4-plane layout (gather source; 16B-aligned inside a 64B row)
        *reinterpret_cast<uint4*>(
            featb4 + (size_t)(d0 >> 5) * PL4 + (size_t)n * 32 + (d0 & 31)) = pk;
    } else if (b < 2628) {
        int idx = (b - 2500) * 256 + t;  // 0..32767
        int c = idx >> 13, n = (idx >> 6) & 127, kp = idx & 63;
        int k = c * 64 + kp;
        float w = (k < DIM) ? Wself[(size_t)k * DIM + n]
                            : Wneigh[(size_t)(k - DIM) * DIM + n];
        Wc[idx] = f2bf(w);
    } else {
        int i = (b - 2628) * 256 + t;
        if (i < NN) cnt[i] = 0;
    }
}

// ---------------------------------------------------------------------------
// Adjacency fill (r0 proven form — r2/r4/r7/r11 variants all measured equal;
// keep the simplest).
// ---------------------------------------------------------------------------
__global__ __launch_bounds__(256) void k_fill(
    const int* __restrict__ src, const int* __restrict__ dst,
    int* __restrict__ cnt, unsigned short* __restrict__ colf)
{
    int e = blockIdx.x * blockDim.x + threadIdx.x;
    if (e < NE) {
        int d = dst[e];
        int pos = atomicAdd(&cnt[d], 1);
        if (pos < CAP) colf[d * CAP + pos] = (unsigned short)src[e];
    }
}

// ---------------------------------------------------------------------------
// Gather + mean v5: XCD-L2-pinned 4-plane reads + NONTEMPORAL hnb writes.
// Mechanism: gather reads 164MB of random 256B rows from a 10.24MB table
// that exceeds the 4MiB per-XCD L2 -> served at L3-random rate (~27us, the
// measured G). Split by dim-plane: class c = blockIdx&3 runs on XCDs {c,c+4}
// (round-robin), reads ONLY plane c (2.56MB -> L2-resident). r1's version of
// this was null because hnb write-allocate evicted the plane; nt-stores fix
// retention. colf/cnt reads stay cached (reused by all 4 classes).
// Wave = 4 neighbor slots x 16 dim-lanes; 4 loads in flight (16 rows).
// ---------------------------------------------------------------------------
__global__ __launch_bounds__(256) void k_gather(
    const unsigned int* __restrict__ fb4,    // featb4 as [4][NN][16] uint
    const int* __restrict__ cnt,
    const unsigned short* __restrict__ colf,
    unsigned int* __restrict__ hnb32)        // hnb as [2][NN][32] uint
{
    int b = blockIdx.x;
    int c = b & 3;                                   // plane / XCD class
    int n = ((b >> 2) << 2) + (threadIdx.x >> 6);    // node
    int lane = threadIdx.x & 63;
    int j = lane >> 4;                               // neighbor slot 0..3
    int u = lane & 15;                               // dim-uint 0..15

    int deg = cnt[n];
    int m = min(deg, CAP);
    int sv = (lane < m) ? (int)colf[n * CAP + lane] : 0;

    const unsigned int* pb = fb4 + (size_t)c * (NN * 16);
    float ax = 0.f, ay = 0.f;
    for (int i = 0; i < m; i += 16) {
        int i0 = i + j, i1 = i + 4 + j, i2 = i + 8 + j, i3 = i + 12 + j;
        int s0 = __shfl(sv, i0), s1 = __shfl(sv, i1);
        int s2 = __shfl(sv, i2), s3 = __shfl(sv, i3);
        unsigned int v0 = pb[s0 * 16 + u];
        unsigned int v1 = pb[s1 * 16 + u];
        unsigned int v2 = pb[s2 * 16 + u];
        unsigned int v3 = pb[s3 * 16 + u];
        if (i0 < m) { ax += bflo2f(v0); ay += bfhi2f(v0); }
        if (i1 < m) { ax += bflo2f(v1); ay += bfhi2f(v1); }
        if (i2 < m) { ax += bflo2f(v2); ay += bfhi2f(v2); }
        if (i3 < m) { ax += bflo2f(v3); ay += bfhi2f(v3); }
    }
    // reduce the 4 neighbor slots
    ax += __shfl_xor(ax, 16); ay += __shfl_xor(ay, 16);
    ax += __shfl_xor(ax, 32); ay += __shfl_xor(ay, 32);
    if (lane < 16) {
        float inv = 1.0f / fmaxf((float)deg, 1.0f);
        unsigned int pk = (unsigned int)f2bf(ax * inv)
                        | ((unsigned int)f2bf(ay * inv) << 16);
        // write into the 2-plane hnb layout the gemm expects:
        // plane = c>>1, column base = (c&1)*32 dims = (c&1)*16 uints
        __builtin_nontemporal_store(
            pk, hnb32 + (size_t)(c >> 1) * (NN * 32)
                      + (size_t)n * 32 + (c & 1) * 16 + u);
    }
}

// ---------------------------------------------------------------------------
// Fused GEMM (r4 proven form, source-swizzled LDS staging) — unchanged.
// ---------------------------------------------------------------------------
__global__ __launch_bounds__(320) void k_gemm(
    const unsigned short* __restrict__ featb,  // [2][NN][64]
    const unsigned short* __restrict__ hnb,    // [2][NN][64]
    const unsigned short* __restrict__ Wc,     // [4][128][64]
    const float* __restrict__ bself, const float* __restrict__ bneigh,
    float* __restrict__ out)                   // [NN,128] fp32
{
    __shared__ unsigned short As[160 * 64];  // 20480 B
    __shared__ unsigned short Bs[128 * 64];  // 16384 B

    int t = threadIdx.x;
    int w = t >> 6;
    int lane = t & 63;
    int base_m = blockIdx.x * 160;

    floatx4 acc[2][8];
    #pragma unroll
    for (int a = 0; a < 2; ++a)
        #pragma unroll
        for (int b = 0; b < 8; ++b) acc[a][b] = (floatx4)0.f;

    for (int c = 0; c < 4; ++c) {
        const unsigned short* srcp =
            ((c < 2) ? featb + (size_t)c * PLANE
                     : hnb + (size_t)(c - 2) * PLANE) + (size_t)base_m * 64;
        #pragma unroll
        for (int it = 0; it < 4; ++it) {          // 1280 slots / 320 threads
            int s = t + it * 320;
            int m = s >> 3, g = s & 7;            // LDS (row m, 16B-granule g)
            const unsigned short* sa = srcp + m * 64 + ((g ^ (m & 7)) << 3);
            __builtin_amdgcn_global_load_lds(
                (const __attribute__((address_space(1))) unsigned int*)sa,
                (__attribute__((address_space(3))) unsigned int*)(As + s * 8),
                16, 0, 0);
        }
        if (t < 256) {
            const unsigned short* bp = Wc + (size_t)c * 128 * 64;
            #pragma unroll
            for (int it = 0; it < 4; ++it) {      // 1024 slots / 256 threads
                int s = t + it * 256;
                int n = s >> 3, g = s & 7;
                const unsigned short* sb = bp + n * 64 + ((g ^ (n & 7)) << 3);
                __builtin_amdgcn_global_load_lds(
                    (const __attribute__((address_space(1))) unsigned int*)sb,
                    (__attribute__((address_space(3))) unsigned int*)(Bs + s * 8),
                    16, 0, 0);
            }
        }
        __syncthreads();

        #pragma unroll
        for (int sstep = 0; sstep < 2; ++sstep) {
            int gk = sstep * 4 + (lane >> 4);     // source 16B-granule wanted
            short8 af[2];
            #pragma unroll
            for (int mt = 0; mt < 2; ++mt) {
                int m = w * 32 + mt * 16 + (lane & 15);
                af[mt] = *reinterpret_cast<const short8*>(
                    As + m * 64 + ((gk ^ (m & 7)) << 3));
            }
            #pragma unroll
            for (int nt = 0; nt < 8; ++nt) {
                int n = nt * 16 + (lane & 15);
                short8 bf = *reinterpret_cast<const short8*>(
                    Bs + n * 64 + ((gk ^ (n & 7)) << 3));
                acc[0][nt] = __builtin_amdgcn_mfma_f32_16x16x32_bf16(
                    af[0], bf, acc[0][nt], 0, 0, 0);
                acc[1][nt] = __builtin_amdgcn_mfma_f32_16x16x32_bf16(
                    af[1], bf, acc[1][nt], 0, 0, 0);
            }
        }
        __syncthreads();
    }

    int colb = lane & 15;
    int quad = lane >> 4;
    #pragma unroll
    for (int nt = 0; nt < 8; ++nt) {
        int col = nt * 16 + colb;
        float bb = bself[col] + bneigh[col];
        #pragma unroll
        for (int mt = 0; mt < 2; ++mt) {
            #pragma unroll
            for (int r = 0; r < 4; ++r) {
                int row = base_m + w * 32 + mt * 16 + quad * 4 + r;
                out[(size_t)row * DIM + col] = acc[mt][nt][r] + bb;
            }
        }
    }
}

// ---------------------------------------------------------------------------
extern "C" void kernel_launch(void* const* d_in, const int* in_sizes, int n_in,
                              void* d_out, int out_size, void* d_ws, size_t ws_size,
                              hipStream_t stream)
{
    const float* feat   = (const float*)d_in[0];
    const int*   src    = (const int*)d_in[1];
    const int*   dst    = (const int*)d_in[2];
    const float* Wself  = (const float*)d_in[3];
    const float* bself  = (const float*)d_in[4];
    const float* Wneigh = (const float*)d_in[5];
    const float* bneigh = (const float*)d_in[6];
    float* out = (float*)d_out;

    // Workspace layout (bytes):
    //   featb2 [2][NN][64] bf16 @ 0           (10,240,000)  gemm source
    //   hnb    [2][NN][64] bf16 @ 10,240,000  (10,240,000)
    //   colf   [NN][CAP]   u16  @ 20,480,000  ( 3,840,000)
    //   Wc     [4][128][64]bf16 @ 24,320,000  (    65,536)
    //   cnt    [NN]        i32  @ 24,385,536  (   160,000)
    //   featb4 [4][NN][32] bf16 @ 24,545,536  (10,240,000)  gather source
    // total 34,785,536 B
    char* ws = (char*)d_ws;
    unsigned short* featb2 = (unsigned short*)(ws);
    unsigned short* hnb    = (unsigned short*)(ws + 10240000);
    unsigned short* colf   = (unsigned short*)(ws + 20480000);
    unsigned short* Wc     = (unsigned short*)(ws + 24320000);
    int*            cnt    = (int*)(ws + 24385536);
    unsigned short* featb4 = (unsigned short*)(ws + 24545536);

    k_prep<<<2785, 256, 0, stream>>>(feat, Wself, Wneigh,
                                     featb2, featb4, Wc, cnt);

    k_fill<<<(NE + 255) / 256, 256, 0, stream>>>(src, dst, cnt, colf);

    k_gather<<<NN, 256, 0, stream>>>(
        (const unsigned int*)featb4, cnt, colf, (unsigned int*)hnb);

    k_gemm<<<NN / 160, 320, 0, stream>>>(featb2, hnb, Wc, bself, bneigh, out);
}

// Round 13
// 145.133 us; speedup vs baseline: 1.1427x; 1.1427x over previous
//
#include <hip/hip_runtime.h>
#include <cstddef>

constexpr int NN  = 40000;   // nodes
constexpr int NE  = 640000;  // edges
constexpr int DIM = 128;     // D_IN == D_OUT
constexpr int CAP = 48;      // per-node neighbor capacity (max deg ~36)
constexpr int PLANE = NN * 64;  // shorts per 64-dim plane

typedef __attribute__((ext_vector_type(8))) short short8;   // 8 bf16 (4 VGPRs)
typedef __attribute__((ext_vector_type(4))) float floatx4;  // MFMA acc

// fp32 -> bf16 with round-to-nearest-even
__device__ __forceinline__ unsigned short f2bf(float x) {
    union { float f; unsigned int i; } v; v.f = x;
    unsigned int u = v.i;
    return (unsigned short)((u + 0x7fffu + ((u >> 16) & 1u)) >> 16);
}
__device__ __forceinline__ float bflo2f(unsigned int u) {   // low bf16 -> f32
    union { unsigned int i; float f; } v; v.i = u << 16; return v.f;
}
__device__ __forceinline__ float bfhi2f(unsigned int u) {   // high bf16 -> f32
    union { unsigned int i; float f; } v; v.i = u & 0xffff0000u; return v.f;
}

// ---------------------------------------------------------------------------
// Prep (r4 proven form): [0..2499] cast feat -> featb[2][NN][64] bf16
//                        [2500..2627] W -> Wc[4][128][64]
//                        [2628..2784] zero cnt
// ---------------------------------------------------------------------------
__global__ __launch_bounds__(256) void k_prep(
    const float* __restrict__ feat, const float* __restrict__ Wself,
    const float* __restrict__ Wneigh, unsigned short* __restrict__ featb,
    unsigned short* __restrict__ Wc, int* __restrict__ cnt)
{
    int b = blockIdx.x, t = threadIdx.x;
    if (b < 2500) {
        int idx8 = b * 256 + t;          // 640000 groups of 8 dims
        int n  = idx8 >> 4;
        int d0 = (idx8 & 15) << 3;
        const float4* fp =
            reinterpret_cast<const float4*>(feat + (size_t)n * DIM + d0);
        float4 v0 = fp[0], v1 = fp[1];
        unsigned int p0 = (unsigned int)f2bf(v0.x) | ((unsigned int)f2bf(v0.y) << 16);
        unsigned int p1 = (unsigned int)f2bf(v0.z) | ((unsigned int)f2bf(v0.w) << 16);
        unsigned int p2 = (unsigned int)f2bf(v1.x) | ((unsigned int)f2bf(v1.y) << 16);
        unsigned int p3 = (unsigned int)f2bf(v1.z) | ((unsigned int)f2bf(v1.w) << 16);
        int plane = d0 >> 6, off = d0 & 63;
        *reinterpret_cast<uint4*>(
            featb + (size_t)plane * PLANE + (size_t)n * 64 + off) =
            make_uint4(p0, p1, p2, p3);
    } else if (b < 2628) {
        int idx = (b - 2500) * 256 + t;
        int c = idx >> 13, n = (idx >> 6) & 127, kp = idx & 63;
        int k = c * 64 + kp;
        float w = (k < DIM) ? Wself[(size_t)k * DIM + n]
                            : Wneigh[(size_t)(k - DIM) * DIM + n];
        Wc[idx] = f2bf(w);
    } else {
        int i = (b - 2628) * 256 + t;
        if (i < NN) cnt[i] = 0;
    }
}

// ---------------------------------------------------------------------------
// Adjacency fill (r0 proven form — all variants measured equal).
// ---------------------------------------------------------------------------
__global__ __launch_bounds__(256) void k_fill(
    const int* __restrict__ src, const int* __restrict__ dst,
    int* __restrict__ cnt, unsigned short* __restrict__ colf)
{
    int e = blockIdx.x * blockDim.x + threadIdx.x;
    if (e < NE) {
        int d = dst[e];
        int pos = atomicAdd(&cnt[d], 1);
        if (pos < CAP) colf[d * CAP + pos] = (unsigned short)src[e];
    }
}

// ---------------------------------------------------------------------------
// Gather + mean v6: instruction-lean single pass.
// r12 profile: gather is VALU/issue-bound (VALUBusy 67%, HBM 8%) — so cut
// instructions/loads per edge, keep the proven 1-wave/node TLP (40k waves).
// Lane = 4 neighbor-subgroups (g=lane>>4) x 16 row-lanes (j=lane&15:
// plane j>>3, uint4 j&7). One uint4 load covers 1/4 row; one wave-load = 4
// FULL neighbor rows (vs 1 row before): per 16 neighbors 4 loads + 4 shfl
// (vs 16+16). Invalid rows zeroed by cndmask (accumulate adds 0). 8 f32
// acc/lane; shfl_xor(16,32) reduce; lanes 0-15 store one uint4 of the mean.
// ---------------------------------------------------------------------------
__global__ __launch_bounds__(256) void k_gather(
    const uint4* __restrict__ fb,            // featb as [2][NN][8] uint4
    const int* __restrict__ cnt,
    const unsigned short* __restrict__ colf,
    uint4* __restrict__ hnb4)                // hnb as [2][NN][8] uint4
{
    int gtid = blockIdx.x * blockDim.x + threadIdx.x;
    int n = gtid >> 6;
    if (n >= NN) return;
    int lane = threadIdx.x & 63;
    int g = lane >> 4;                       // neighbor subgroup 0..3
    int j = lane & 15;                       // row slice: plane j>>3, uint4 j&7

    int deg = cnt[n];
    int m = min(deg, CAP);
    int sv = (lane < m) ? (int)colf[n * CAP + lane] : 0;

    size_t rb = (size_t)(j >> 3) * (NN * 8) + (j & 7);  // plane base + slice
    float a0 = 0.f, a1 = 0.f, a2 = 0.f, a3 = 0.f;
    float a4 = 0.f, a5 = 0.f, a6 = 0.f, a7 = 0.f;

    for (int i = 0; i < m; i += 16) {
        int i0 = i + g, i1 = i + 4 + g, i2 = i + 8 + g, i3 = i + 12 + g;
        int s0 = __shfl(sv, i0), s1 = __shfl(sv, i1);
        int s2 = __shfl(sv, i2), s3 = __shfl(sv, i3);
        uint4 v0 = fb[rb + (size_t)s0 * 8];
        uint4 v1 = fb[rb + (size_t)s1 * 8];
        uint4 v2 = fb[rb + (size_t)s2 * 8];
        uint4 v3 = fb[rb + (size_t)s3 * 8];
        unsigned int z0 = (i0 < m) ? 0xffffffffu : 0u;
        unsigned int z1 = (i1 < m) ? 0xffffffffu : 0u;
        unsigned int z2 = (i2 < m) ? 0xffffffffu : 0u;
        unsigned int z3 = (i3 < m) ? 0xffffffffu : 0u;
        v0.x &= z0; v0.y &= z0; v0.z &= z0; v0.w &= z0;
        v1.x &= z1; v1.y &= z1; v1.z &= z1; v1.w &= z1;
        v2.x &= z2; v2.y &= z2; v2.z &= z2; v2.w &= z2;
        v3.x &= z3; v3.y &= z3; v3.z &= z3; v3.w &= z3;
        a0 += bflo2f(v0.x); a1 += bfhi2f(v0.x);
        a2 += bflo2f(v0.y); a3 += bfhi2f(v0.y);
        a4 += bflo2f(v0.z); a5 += bfhi2f(v0.z);
        a6 += bflo2f(v0.w); a7 += bfhi2f(v0.w);
        a0 += bflo2f(v1.x); a1 += bfhi2f(v1.x);
        a2 += bflo2f(v1.y); a3 += bfhi2f(v1.y);
        a4 += bflo2f(v1.z); a5 += bfhi2f(v1.z);
        a6 += bflo2f(v1.w); a7 += bfhi2f(v1.w);
        a0 += bflo2f(v2.x); a1 += bfhi2f(v2.x);
        a2 += bflo2f(v2.y); a3 += bfhi2f(v2.y);
        a4 += bflo2f(v2.z); a5 += bfhi2f(v2.z);
        a6 += bflo2f(v2.w); a7 += bfhi2f(v2.w);
        a0 += bflo2f(v3.x); a1 += bfhi2f(v3.x);
        a2 += bflo2f(v3.y); a3 += bfhi2f(v3.y);
        a4 += bflo2f(v3.z); a5 += bfhi2f(v3.z);
        a6 += bflo2f(v3.w); a7 += bfhi2f(v3.w);
    }

    // reduce across the 4 neighbor subgroups
    a0 += __shfl_xor(a0, 16); a1 += __shfl_xor(a1, 16);
    a2 += __shfl_xor(a2, 16); a3 += __shfl_xor(a3, 16);
    a4 += __shfl_xor(a4, 16); a5 += __shfl_xor(a5, 16);
    a6 += __shfl_xor(a6, 16); a7 += __shfl_xor(a7, 16);
    a0 += __shfl_xor(a0, 32); a1 += __shfl_xor(a1, 32);
    a2 += __shfl_xor(a2, 32); a3 += __shfl_xor(a3, 32);
    a4 += __shfl_xor(a4, 32); a5 += __shfl_xor(a5, 32);
    a6 += __shfl_xor(a6, 32); a7 += __shfl_xor(a7, 32);

    if (lane < 16) {
        float inv = 1.0f / fmaxf((float)deg, 1.0f);
        uint4 pk;
        pk.x = (unsigned int)f2bf(a0 * inv) | ((unsigned int)f2bf(a1 * inv) << 16);
        pk.y = (unsigned int)f2bf(a2 * inv) | ((unsigned int)f2bf(a3 * inv) << 16);
        pk.z = (unsigned int)f2bf(a4 * inv) | ((unsigned int)f2bf(a5 * inv) << 16);
        pk.w = (unsigned int)f2bf(a6 * inv) | ((unsigned int)f2bf(a7 * inv) << 16);
        hnb4[rb + (size_t)n * 8] = pk;
    }
}

// ---------------------------------------------------------------------------
// Fused GEMM (r4 proven form, source-swizzled LDS staging) — 148.3us config.
// ---------------------------------------------------------------------------
__global__ __launch_bounds__(320) void k_gemm(
    const unsigned short* __restrict__ featb,  // [2][NN][64]
    const unsigned short* __restrict__ hnb,    // [2][NN][64]
    const unsigned short* __restrict__ Wc,     // [4][128][64]
    const float* __restrict__ bself, const float* __restrict__ bneigh,
    float* __restrict__ out)                   // [NN,128] fp32
{
    __shared__ unsigned short As[160 * 64];  // 20480 B
    __shared__ unsigned short Bs[128 * 64];  // 16384 B

    int t = threadIdx.x;
    int w = t >> 6;
    int lane = t & 63;
    int base_m = blockIdx.x * 160;

    floatx4 acc[2][8];
    #pragma unroll
    for (int a = 0; a < 2; ++a)
        #pragma unroll
        for (int b = 0; b < 8; ++b) acc[a][b] = (floatx4)0.f;

    for (int c = 0; c < 4; ++c) {
        const unsigned short* srcp =
            ((c < 2) ? featb + (size_t)c * PLANE
                     : hnb + (size_t)(c - 2) * PLANE) + (size_t)base_m * 64;
        #pragma unroll
        for (int it = 0; it < 4; ++it) {          // 1280 slots / 320 threads
            int s = t + it * 320;
            int m = s >> 3, g = s & 7;            // LDS (row m, 16B-granule g)
            const unsigned short* sa = srcp + m * 64 + ((g ^ (m & 7)) << 3);
            __builtin_amdgcn_global_load_lds(
                (const __attribute__((address_space(1))) unsigned int*)sa,
                (__attribute__((address_space(3))) unsigned int*)(As + s * 8),
                16, 0, 0);
        }
        if (t < 256) {
            const unsigned short* bp = Wc + (size_t)c * 128 * 64;
            #pragma unroll
            for (int it = 0; it < 4; ++it) {      // 1024 slots / 256 threads
                int s = t + it * 256;
                int n = s >> 3, g = s & 7;
                const unsigned short* sb = bp + n * 64 + ((g ^ (n & 7)) << 3);
                __builtin_amdgcn_global_load_lds(
                    (const __attribute__((address_space(1))) unsigned int*)sb,
                    (__attribute__((address_space(3))) unsigned int*)(Bs + s * 8),
                    16, 0, 0);
            }
        }
        __syncthreads();

        #pragma unroll
        for (int sstep = 0; sstep < 2; ++sstep) {
            int gk = sstep * 4 + (lane >> 4);     // source 16B-granule wanted
            short8 af[2];
            #pragma unroll
            for (int mt = 0; mt < 2; ++mt) {
                int m = w * 32 + mt * 16 + (lane & 15);
                af[mt] = *reinterpret_cast<const short8*>(
                    As + m * 64 + ((gk ^ (m & 7)) << 3));
            }
            #pragma unroll
            for (int nt = 0; nt < 8; ++nt) {
                int n = nt * 16 + (lane & 15);
                short8 bf = *reinterpret_cast<const short8*>(
                    Bs + n * 64 + ((gk ^ (n & 7)) << 3));
                acc[0][nt] = __builtin_amdgcn_mfma_f32_16x16x32_bf16(
                    af[0], bf, acc[0][nt], 0, 0, 0);
                acc[1][nt] = __builtin_amdgcn_mfma_f32_16x16x32_bf16(
                    af[1], bf, acc[1][nt], 0, 0, 0);
            }
        }
        __syncthreads();
    }

    int colb = lane & 15;
    int quad = lane >> 4;
    #pragma unroll
    for (int nt = 0; nt < 8; ++nt) {
        int col = nt * 16 + colb;
        float bb = bself[col] + bneigh[col];
        #pragma unroll
        for (int mt = 0; mt < 2; ++mt) {
            #pragma unroll
            for (int r = 0; r < 4; ++r) {
                int row = base_m + w * 32 + mt * 16 + quad * 4 + r;
                out[(size_t)row * DIM + col] = acc[mt][nt][r] + bb;
            }
        }
    }
}

// ---------------------------------------------------------------------------
extern "C" void kernel_launch(void* const* d_in, const int* in_sizes, int n_in,
                              void* d_out, int out_size, void* d_ws, size_t ws_size,
                              hipStream_t stream)
{
    const float* feat   = (const float*)d_in[0];
    const int*   src    = (const int*)d_in[1];
    const int*   dst    = (const int*)d_in[2];
    const float* Wself  = (const float*)d_in[3];
    const float* bself  = (const float*)d_in[4];
    const float* Wneigh = (const float*)d_in[5];
    const float* bneigh = (const float*)d_in[6];
    float* out = (float*)d_out;

    // Workspace layout (bytes):
    //   featb [2][NN][64] bf16 @ 0           (10,240,000)
    //   hnb   [2][NN][64] bf16 @ 10,240,000  (10,240,000)
    //   colf  [NN][CAP]   u16  @ 20,480,000  ( 3,840,000)
    //   Wc    [4][128][64]bf16 @ 24,320,000  (    65,536)
    //   cnt   [NN]        i32  @ 24,385,536  (   160,000)
    // total 24,545,536 B
    char* ws = (char*)d_ws;
    unsigned short* featb = (unsigned short*)(ws);
    unsigned short* hnb   = (unsigned short*)(ws + 10240000);
    unsigned short* colf  = (unsigned short*)(ws + 20480000);
    unsigned short* Wc    = (unsigned short*)(ws + 24320000);
    int*            cnt   = (int*)(ws + 24385536);

    k_prep<<<2785, 256, 0, stream>>>(feat, Wself, Wneigh, featb, Wc, cnt);

    k_fill<<<(NE + 255) / 256, 256, 0, stream>>>(src, dst, cnt, colf);

    k_gather<<<(NN * 64) / 256, 256, 0, stream>>>(
        (const uint4*)featb, cnt, colf, (uint4*)hnb);

    k_gemm<<<NN / 160, 320, 0, stream>>>(featb, hnb, Wc, bself, bneigh, out);
}